// Round 7
// baseline (681.352 us; speedup 1.0000x reference)
//
#include <hip/hip_runtime.h>
#include <math.h>

#define N_NODES 50000
#define N_EDGES 640000
#define FDIM 128
#define NCLS 16
#define BN_EPS 1e-5f
#define NBLK 512          // 2 blocks/CU * 256 CUs — co-resident persistent grid
#define NBS 196           // ceil(50000/256) scan blocks

// ---- bf16 pack/unpack (RNE) ----
__device__ __forceinline__ unsigned pack_bf16x2(float lo, float hi) {
    unsigned ul = __float_as_uint(lo);
    unsigned uh = __float_as_uint(hi);
    ul += 0x7fff + ((ul >> 16) & 1);
    uh += 0x7fff + ((uh >> 16) & 1);
    return (ul >> 16) | (uh & 0xffff0000u);
}
__device__ __forceinline__ float bf_lo(unsigned u) { return __uint_as_float(u << 16); }
__device__ __forceinline__ float bf_hi(unsigned u) { return __uint_as_float(u & 0xffff0000u); }

// ---- device-scope grid barrier (all NBLK blocks resident by construction) ----
__device__ __forceinline__ void grid_barrier(int* cnt, int* gen) {
    __syncthreads();
    if (threadIdx.x == 0) {
        __threadfence();   // release all prior writes (device scope)
        int g = __hip_atomic_load(gen, __ATOMIC_RELAXED, __HIP_MEMORY_SCOPE_AGENT);
        int a = __hip_atomic_fetch_add(cnt, 1, __ATOMIC_ACQ_REL, __HIP_MEMORY_SCOPE_AGENT);
        if (a == NBLK - 1) {
            __hip_atomic_store(cnt, 0, __ATOMIC_RELAXED, __HIP_MEMORY_SCOPE_AGENT);
            __hip_atomic_fetch_add(gen, 1, __ATOMIC_RELEASE, __HIP_MEMORY_SCOPE_AGENT);
        } else {
            while (__hip_atomic_load(gen, __ATOMIC_ACQUIRE, __HIP_MEMORY_SCOPE_AGENT) == g)
                __builtin_amdgcn_s_sleep(8);
        }
        __threadfence();
    }
    __syncthreads();
}

// ---------------- THE mega kernel: whole GCN forward in one dispatch ----------------
__global__ __launch_bounds__(256, 2) void mega_kernel(
        int* __restrict__ bar,                 // [0]=cnt [1]=gen, pre-zeroed
        int* __restrict__ deg,                 // pre-zeroed
        int* __restrict__ cursor,
        int* __restrict__ offs,
        int* __restrict__ partials,
        float* __restrict__ dinv,
        int2* __restrict__ csr_sw,
        unsigned* __restrict__ bufA,
        float* __restrict__ Zbuf,
        float* __restrict__ W2c,
        float* __restrict__ bc2,
        float4* __restrict__ fusedq,
        const float* __restrict__ seq,
        const int* __restrict__ eidx,
        const float* __restrict__ W1,
        const float* __restrict__ b1,
        const float* __restrict__ gamma,
        const float* __restrict__ beta,
        const float* __restrict__ rmean,
        const float* __restrict__ rvar,
        const float* __restrict__ W2,
        const float* __restrict__ b2,
        const float* __restrict__ Wc,
        const float* __restrict__ bc,
        float* __restrict__ out) {
    __shared__ __align__(16) char smem[24832];   // max over stages (gemm: 8448+16384)
    const int bid = blockIdx.x;
    const int tid = threadIdx.x;
    int* bar_cnt = bar;
    int* bar_gen = bar + 1;
    const int4* src4 = (const int4*)eidx;
    const int4* dst4 = (const int4*)(eidx + N_EDGES);

    // ================= S1: count in-degrees (deg pre-zeroed by host memset) =================
    for (int t = bid * 256 + tid; t < N_EDGES / 4; t += NBLK * 256) {
        int4 d = dst4[t];
        atomicAdd(&deg[d.x], 1);
        atomicAdd(&deg[d.y], 1);
        atomicAdd(&deg[d.z], 1);
        atomicAdd(&deg[d.w], 1);
    }
    grid_barrier(bar_cnt, bar_gen);

    // ================= S2: block-local exclusive scans + dinv + cursor zero =================
    if (bid < NBS) {
        int* s = (int*)smem;
        int gid = bid * 256 + tid;
        int v = (gid < N_NODES) ? deg[gid] : 0;
        if (gid < N_NODES) {
            dinv[gid] = rsqrtf((float)(v + 1));  // +1 self loop
            cursor[gid] = 0;
        }
        s[tid] = v;
        __syncthreads();
        for (int off = 1; off < 256; off <<= 1) {
            int t2 = (tid >= off) ? s[tid - off] : 0;
            __syncthreads();
            s[tid] += t2;
            __syncthreads();
        }
        if (gid <= N_NODES) offs[gid] = s[tid] - v;   // block-local exclusive
        if (tid == 255) partials[bid] = s[255];
    }
    grid_barrier(bar_cnt, bar_gen);

    // ================= S3: scan the 196 block totals (block 0) =================
    if (bid == 0) {
        int* s = (int*)smem;
        int v = (tid < NBS) ? partials[tid] : 0;
        s[tid] = v;
        __syncthreads();
        for (int off = 1; off < 256; off <<= 1) {
            int t2 = (tid >= off) ? s[tid - off] : 0;
            __syncthreads();
            s[tid] += t2;
            __syncthreads();
        }
        if (tid < NBS) partials[tid] = s[tid] - v;
    }
    grid_barrier(bar_cnt, bar_gen);

    // ================= S4: fill CSR (625) | fold weights (8) | gemm tiles (782) =================
    for (int vb = bid; vb < 1415; vb += NBLK) {
        if (vb < 625) {
            int t = vb * 256 + tid;
            int4 sv = src4[t];
            int4 dv = dst4[t];
            {
                int pos = offs[dv.x] + partials[dv.x >> 8] + atomicAdd(&cursor[dv.x], 1);
                csr_sw[pos] = make_int2(sv.x, __float_as_int(dinv[sv.x]));
            }
            {
                int pos = offs[dv.y] + partials[dv.y >> 8] + atomicAdd(&cursor[dv.y], 1);
                csr_sw[pos] = make_int2(sv.y, __float_as_int(dinv[sv.y]));
            }
            {
                int pos = offs[dv.z] + partials[dv.z >> 8] + atomicAdd(&cursor[dv.z], 1);
                csr_sw[pos] = make_int2(sv.z, __float_as_int(dinv[sv.z]));
            }
            {
                int pos = offs[dv.w] + partials[dv.w >> 8] + atomicAdd(&cursor[dv.w], 1);
                csr_sw[pos] = make_int2(sv.w, __float_as_int(dinv[sv.w]));
            }
        } else if (vb < 633) {
            int gid = (vb - 625) * 256 + tid;          // 0..2047
            int r = gid >> 4, c = gid & 15;
            float acc = 0.f;
#pragma unroll 8
            for (int k = 0; k < 128; k++) acc += W2[r * 128 + k] * Wc[k * 16 + c];
            W2c[gid] = acc;
            if (vb == 625) {
                if (tid < 16) {
                    float a = bc[tid];
                    for (int k = 0; k < 128; k++) a += b2[k] * Wc[k * 16 + tid];
                    bc2[tid] = a;
                }
                if (tid < 64) {
                    int c0 = tid * 2, c1 = c0 + 1;
                    float sc0 = gamma[c0] * rsqrtf(rvar[c0] + BN_EPS);
                    float sc1 = gamma[c1] * rsqrtf(rvar[c1] + BN_EPS);
                    float sh0 = (b1[c0] - rmean[c0]) * sc0 + beta[c0];
                    float sh1 = (b1[c1] - rmean[c1]) * sc1 + beta[c1];
                    fusedq[tid] = make_float4(sc0, sh0, sc1, sh1);
                }
            }
        } else {
            // -------- gemm tile: 64 rows x 128 cols, BK=32 --------
            float* sX = (float*)smem;                  // 64*33
            float* sW = (float*)(smem + 64 * 33 * 4);  // 32*128
            float4* sW4 = (float4*)sW;
            int r0 = (vb - 633) * 64;
            int colg = tid & 15, rowt = tid >> 4;
            float acc[4][8];
#pragma unroll
            for (int i = 0; i < 4; i++)
#pragma unroll
                for (int j = 0; j < 8; j++) acc[i][j] = 0.f;
            const float4* X4 = (const float4*)seq;
            const float4* W4 = (const float4*)W1;
#pragma unroll
            for (int kt = 0; kt < 4; kt++) {
#pragma unroll
                for (int i = 0; i < 2; i++) {
                    int idx = tid + i * 256;
                    int row = idx >> 3, k4 = idx & 7;
                    float4 v = make_float4(0.f, 0.f, 0.f, 0.f);
                    if (r0 + row < N_NODES) v = X4[(size_t)(r0 + row) * 32 + kt * 8 + k4];
                    float* p = &sX[row * 33 + k4 * 4];
                    p[0] = v.x; p[1] = v.y; p[2] = v.z; p[3] = v.w;
                }
#pragma unroll
                for (int i = 0; i < 4; i++) {
                    int idx = tid + i * 256;
                    int kk = idx >> 5, c4 = idx & 31;
                    sW4[kk * 32 + c4] = W4[(size_t)(kt * 32 + kk) * 32 + c4];
                }
                __syncthreads();
#pragma unroll 8
                for (int k = 0; k < 32; k++) {
                    float4 w0 = sW4[k * 32 + colg * 2];
                    float4 w1 = sW4[k * 32 + colg * 2 + 1];
                    float xs[4];
#pragma unroll
                    for (int i = 0; i < 4; i++) xs[i] = sX[(rowt * 4 + i) * 33 + k];
#pragma unroll
                    for (int i = 0; i < 4; i++) {
                        acc[i][0] += xs[i] * w0.x; acc[i][1] += xs[i] * w0.y;
                        acc[i][2] += xs[i] * w0.z; acc[i][3] += xs[i] * w0.w;
                        acc[i][4] += xs[i] * w1.x; acc[i][5] += xs[i] * w1.y;
                        acc[i][6] += xs[i] * w1.z; acc[i][7] += xs[i] * w1.w;
                    }
                }
                __syncthreads();
            }
#pragma unroll
            for (int i = 0; i < 4; i++) {
                int row = r0 + rowt * 4 + i;
                if (row < N_NODES) {
                    uint4 pv;
                    pv.x = pack_bf16x2(acc[i][0], acc[i][1]);
                    pv.y = pack_bf16x2(acc[i][2], acc[i][3]);
                    pv.z = pack_bf16x2(acc[i][4], acc[i][5]);
                    pv.w = pack_bf16x2(acc[i][6], acc[i][7]);
                    *((uint4*)(bufA + (size_t)row * 64 + colg * 4)) = pv;
                }
            }
        }
        __syncthreads();
    }
    grid_barrier(bar_cnt, bar_gen);

    // ================= S5: layer-1 agg (1 wave/node) + BN + ReLU + @W2c -> Z =================
    {
        float* sH = (float*)smem;                      // [4][128] per-wave regions
        int w = tid >> 6, l = tid & 63;
        int c = l & 15, q = l >> 4;
        float wreg[32];                                // W2c slice, loop-invariant
#pragma unroll
        for (int i = 0; i < 32; i++) wreg[i] = W2c[(q * 32 + i) * 16 + c];

        for (int vb = bid; vb < N_NODES / 4; vb += NBLK) {
            int node = vb * 4 + w;
            int beg = __builtin_amdgcn_readfirstlane(offs[node] + partials[node >> 8]);
            int end = __builtin_amdgcn_readfirstlane(offs[node + 1] + partials[(node + 1) >> 8]);
            float di = dinv[node];

            unsigned hv = bufA[(size_t)node * 64 + l];
            float n2 = di * di;
            float acc0 = bf_lo(hv) * n2, acc1 = bf_hi(hv) * n2;   // self loop

            int e = beg;
            for (; e + 8 <= end; e += 8) {             // 8 full-wave row loads in flight
                int2 a0 = csr_sw[e];     int2 a1 = csr_sw[e + 1];
                int2 a2 = csr_sw[e + 2]; int2 a3 = csr_sw[e + 3];
                int2 a4 = csr_sw[e + 4]; int2 a5 = csr_sw[e + 5];
                int2 a6 = csr_sw[e + 6]; int2 a7 = csr_sw[e + 7];
                unsigned u0 = bufA[(size_t)a0.x * 64 + l];
                unsigned u1 = bufA[(size_t)a1.x * 64 + l];
                unsigned u2 = bufA[(size_t)a2.x * 64 + l];
                unsigned u3 = bufA[(size_t)a3.x * 64 + l];
                unsigned u4 = bufA[(size_t)a4.x * 64 + l];
                unsigned u5 = bufA[(size_t)a5.x * 64 + l];
                unsigned u6 = bufA[(size_t)a6.x * 64 + l];
                unsigned u7 = bufA[(size_t)a7.x * 64 + l];
                float w0 = __int_as_float(a0.y) * di, w1 = __int_as_float(a1.y) * di;
                float w2 = __int_as_float(a2.y) * di, w3 = __int_as_float(a3.y) * di;
                float w4 = __int_as_float(a4.y) * di, w5 = __int_as_float(a5.y) * di;
                float w6 = __int_as_float(a6.y) * di, w7 = __int_as_float(a7.y) * di;
                acc0 += bf_lo(u0) * w0 + bf_lo(u1) * w1 + bf_lo(u2) * w2 + bf_lo(u3) * w3
                      + bf_lo(u4) * w4 + bf_lo(u5) * w5 + bf_lo(u6) * w6 + bf_lo(u7) * w7;
                acc1 += bf_hi(u0) * w0 + bf_hi(u1) * w1 + bf_hi(u2) * w2 + bf_hi(u3) * w3
                      + bf_hi(u4) * w4 + bf_hi(u5) * w5 + bf_hi(u6) * w6 + bf_hi(u7) * w7;
            }
            while (e < end) {                          // masked 4-batch tail (parallel, no serial chain)
                int i0 = e,     i1 = e + 1 < end ? e + 1 : end - 1;
                int i2 = e + 2 < end ? e + 2 : end - 1;
                int i3 = e + 3 < end ? e + 3 : end - 1;
                int2 a0 = csr_sw[i0]; int2 a1 = csr_sw[i1];
                int2 a2 = csr_sw[i2]; int2 a3 = csr_sw[i3];
                unsigned u0 = bufA[(size_t)a0.x * 64 + l];
                unsigned u1 = bufA[(size_t)a1.x * 64 + l];
                unsigned u2 = bufA[(size_t)a2.x * 64 + l];
                unsigned u3 = bufA[(size_t)a3.x * 64 + l];
                float w0 = __int_as_float(a0.y) * di;
                float w1 = (e + 1 < end) ? __int_as_float(a1.y) * di : 0.f;
                float w2 = (e + 2 < end) ? __int_as_float(a2.y) * di : 0.f;
                float w3 = (e + 3 < end) ? __int_as_float(a3.y) * di : 0.f;
                acc0 += bf_lo(u0) * w0 + bf_lo(u1) * w1 + bf_lo(u2) * w2 + bf_lo(u3) * w3;
                acc1 += bf_hi(u0) * w0 + bf_hi(u1) * w1 + bf_hi(u2) * w2 + bf_hi(u3) * w3;
                e += 4;
            }

            // fused BN affine + ReLU (lane l holds features 2l, 2l+1)
            float4 qv = fusedq[l];
            float a0 = fmaxf(acc0 * qv.x + qv.y, 0.f);
            float a1 = fmaxf(acc1 * qv.z + qv.w, 0.f);

            // in-wave transpose through LDS (wave-private region, no barrier)
            ((float2*)&sH[w * 128])[l] = make_float2(a0, a1);
            float z = 0.f;
            const float4* row4 = (const float4*)&sH[w * 128 + q * 32];
#pragma unroll
            for (int i = 0; i < 8; i++) {
                float4 v = row4[i];
                z += v.x * wreg[i * 4] + v.y * wreg[i * 4 + 1]
                   + v.z * wreg[i * 4 + 2] + v.w * wreg[i * 4 + 3];
            }
            z += __shfl_xor(z, 16);
            z += __shfl_xor(z, 32);
            if (l < 16) Zbuf[(size_t)node * NCLS + l] = z;
        }
    }
    grid_barrier(bar_cnt, bar_gen);

    // ================= S6: layer-2 agg on Z (16-wide) + bc2 -> out =================
    {
        int grp = tid >> 4, c = tid & 15;
        for (int vb = bid; vb < N_NODES / 16; vb += NBLK) {
            int node = vb * 16 + grp;
            int beg = offs[node] + partials[node >> 8];
            int end = offs[node + 1] + partials[(node + 1) >> 8];
            float di = dinv[node];

            float acc = Zbuf[(size_t)node * NCLS + c] * di * di;
            int e = beg;
            for (; e + 8 <= end; e += 8) {
                int2 a0 = csr_sw[e],     a1 = csr_sw[e + 1];
                int2 a2 = csr_sw[e + 2], a3 = csr_sw[e + 3];
                int2 a4 = csr_sw[e + 4], a5 = csr_sw[e + 5];
                int2 a6 = csr_sw[e + 6], a7 = csr_sw[e + 7];
                float v0 = Zbuf[(size_t)a0.x * NCLS + c];
                float v1 = Zbuf[(size_t)a1.x * NCLS + c];
                float v2 = Zbuf[(size_t)a2.x * NCLS + c];
                float v3 = Zbuf[(size_t)a3.x * NCLS + c];
                float v4 = Zbuf[(size_t)a4.x * NCLS + c];
                float v5 = Zbuf[(size_t)a5.x * NCLS + c];
                float v6 = Zbuf[(size_t)a6.x * NCLS + c];
                float v7 = Zbuf[(size_t)a7.x * NCLS + c];
                acc += v0 * (__int_as_float(a0.y) * di) + v1 * (__int_as_float(a1.y) * di)
                     + v2 * (__int_as_float(a2.y) * di) + v3 * (__int_as_float(a3.y) * di)
                     + v4 * (__int_as_float(a4.y) * di) + v5 * (__int_as_float(a5.y) * di)
                     + v6 * (__int_as_float(a6.y) * di) + v7 * (__int_as_float(a7.y) * di);
            }
            for (; e < end; e++) {
                int2 a = csr_sw[e];
                acc += Zbuf[(size_t)a.x * NCLS + c] * (__int_as_float(a.y) * di);
            }
            out[(size_t)node * NCLS + c] = acc + bc2[c];
        }
    }
}

// ---------------- Launch ----------------
extern "C" void kernel_launch(void* const* d_in, const int* in_sizes, int n_in,
                              void* d_out, int out_size, void* d_ws, size_t ws_size,
                              hipStream_t stream) {
    const float* seq   = (const float*)d_in[0];
    const int*   eidx  = (const int*)d_in[1];
    const float* W1    = (const float*)d_in[2];
    const float* b1    = (const float*)d_in[3];
    const float* gamma = (const float*)d_in[4];
    const float* beta  = (const float*)d_in[5];
    const float* rmean = (const float*)d_in[6];
    const float* rvar  = (const float*)d_in[7];
    const float* W2    = (const float*)d_in[8];
    const float* b2    = (const float*)d_in[9];
    const float* Wc    = (const float*)d_in[10];
    const float* bc    = (const float*)d_in[11];

    char* ws = (char*)d_ws;
    size_t off = 0;
    auto alloc = [&](size_t bytes) -> void* {
        void* p = ws + off;
        off = (off + bytes + 255) & ~(size_t)255;
        return p;
    };
    int*    bar      = (int*)alloc(256);                    // [cnt, gen] — zeroed below
    int*    deg      = (int*)alloc(N_NODES * 4);            // contiguous with bar: one memset
    int*    cursor   = (int*)alloc(N_NODES * 4);
    int*    offs     = (int*)alloc((N_NODES + 1) * 4);
    int*    partials = (int*)alloc(256 * 4);
    float*  dinv     = (float*)alloc(N_NODES * 4);
    int2*   csr_sw   = (int2*)alloc((size_t)N_EDGES * 8);
    float*  W2c      = (float*)alloc(FDIM * NCLS * 4);
    float*  bc2      = (float*)alloc(NCLS * 4);
    float4* fusedq   = (float4*)alloc(64 * 16);
    unsigned* bufA   = (unsigned*)alloc((size_t)N_NODES * (FDIM / 2) * 4);  // bf16 packed
    float*  Zbuf     = (float*)alloc((size_t)N_NODES * NCLS * 4);

    hipMemsetAsync(bar, 0, 256 + (size_t)N_NODES * 4, stream);   // bar + deg
    mega_kernel<<<NBLK, 256, 0, stream>>>(bar, deg, cursor, offs, partials, dinv,
                                          csr_sw, bufA, Zbuf, W2c, bc2, fusedq,
                                          seq, eidx, W1, b1, gamma, beta, rmean, rvar,
                                          W2, b2, Wc, bc, (float*)d_out);
}

// Round 8
// 230.793 us; speedup vs baseline: 2.9522x; 2.9522x over previous
//
#include <hip/hip_runtime.h>
#include <math.h>

#define N_NODES 50000
#define N_EDGES 640000
#define FDIM 128
#define NCLS 16
#define BN_EPS 1e-5f
#define NBS 196           // ceil(50000/256) scan blocks
#define NBG 782           // ceil(50000/64) gemm tiles

// ---- bf16 pack/unpack (RNE) ----
__device__ __forceinline__ unsigned pack_bf16x2(float lo, float hi) {
    unsigned ul = __float_as_uint(lo);
    unsigned uh = __float_as_uint(hi);
    ul += 0x7fff + ((ul >> 16) & 1);
    uh += 0x7fff + ((uh >> 16) & 1);
    return (ul >> 16) | (uh & 0xffff0000u);
}
__device__ __forceinline__ float bf_lo(unsigned u) { return __uint_as_float(u << 16); }
__device__ __forceinline__ float bf_hi(unsigned u) { return __uint_as_float(u & 0xffff0000u); }

// ============ K1: gemm (blocks 0..781) | count_deg (782..1406) | fold (1407..1414) ============
__global__ __launch_bounds__(256) void gemm_count_fold_kernel(
        const float* __restrict__ seq, const float* __restrict__ W1,
        unsigned* __restrict__ bufA,
        const int* __restrict__ eidx, int* __restrict__ deg,
        const float* __restrict__ W2, const float* __restrict__ Wc,
        const float* __restrict__ b1, const float* __restrict__ b2,
        const float* __restrict__ bc, const float* __restrict__ gamma,
        const float* __restrict__ beta, const float* __restrict__ rmean,
        const float* __restrict__ rvar,
        float* __restrict__ W2c, float* __restrict__ bc2, float4* __restrict__ fusedq) {
    __shared__ __align__(16) char smem[24832];
    int tid = threadIdx.x;
    int bid = blockIdx.x;

    if (bid < NBG) {
        // -------- gemm tile: 64 rows x 128 cols, BK=32, bf16 out --------
        float* sX = (float*)smem;                  // 64*33
        float* sW = (float*)(smem + 64 * 33 * 4);  // 32*128
        float4* sW4 = (float4*)sW;
        int r0 = bid * 64;
        int colg = tid & 15, rowt = tid >> 4;
        float acc[4][8];
#pragma unroll
        for (int i = 0; i < 4; i++)
#pragma unroll
            for (int j = 0; j < 8; j++) acc[i][j] = 0.f;
        const float4* X4 = (const float4*)seq;
        const float4* W4 = (const float4*)W1;
#pragma unroll
        for (int kt = 0; kt < 4; kt++) {
#pragma unroll
            for (int i = 0; i < 2; i++) {
                int idx = tid + i * 256;
                int row = idx >> 3, k4 = idx & 7;
                float4 v = make_float4(0.f, 0.f, 0.f, 0.f);
                if (r0 + row < N_NODES) v = X4[(size_t)(r0 + row) * 32 + kt * 8 + k4];
                float* p = &sX[row * 33 + k4 * 4];
                p[0] = v.x; p[1] = v.y; p[2] = v.z; p[3] = v.w;
            }
#pragma unroll
            for (int i = 0; i < 4; i++) {
                int idx = tid + i * 256;
                int kk = idx >> 5, c4 = idx & 31;
                sW4[kk * 32 + c4] = W4[(size_t)(kt * 32 + kk) * 32 + c4];
            }
            __syncthreads();
#pragma unroll 8
            for (int k = 0; k < 32; k++) {
                float4 w0 = sW4[k * 32 + colg * 2];
                float4 w1 = sW4[k * 32 + colg * 2 + 1];
                float xs[4];
#pragma unroll
                for (int i = 0; i < 4; i++) xs[i] = sX[(rowt * 4 + i) * 33 + k];
#pragma unroll
                for (int i = 0; i < 4; i++) {
                    acc[i][0] += xs[i] * w0.x; acc[i][1] += xs[i] * w0.y;
                    acc[i][2] += xs[i] * w0.z; acc[i][3] += xs[i] * w0.w;
                    acc[i][4] += xs[i] * w1.x; acc[i][5] += xs[i] * w1.y;
                    acc[i][6] += xs[i] * w1.z; acc[i][7] += xs[i] * w1.w;
                }
            }
            __syncthreads();
        }
#pragma unroll
        for (int i = 0; i < 4; i++) {
            int row = r0 + rowt * 4 + i;
            if (row < N_NODES) {
                uint4 pv;
                pv.x = pack_bf16x2(acc[i][0], acc[i][1]);
                pv.y = pack_bf16x2(acc[i][2], acc[i][3]);
                pv.z = pack_bf16x2(acc[i][4], acc[i][5]);
                pv.w = pack_bf16x2(acc[i][6], acc[i][7]);
                *((uint4*)(bufA + (size_t)row * 64 + colg * 4)) = pv;
            }
        }
    } else if (bid < NBG + 625) {
        // -------- count in-degrees: 4 edges/thread, int4 reads --------
        const int4* dst4 = (const int4*)(eidx + N_EDGES);
        int t = (bid - NBG) * 256 + tid;
        int4 d = dst4[t];
        atomicAdd(&deg[d.x], 1);
        atomicAdd(&deg[d.y], 1);
        atomicAdd(&deg[d.z], 1);
        atomicAdd(&deg[d.w], 1);
    } else {
        // -------- fold: W2c = W2@Wc, bc2 = b2@Wc + bc, BN affine --------
        int fb = bid - (NBG + 625);                // 0..7
        int gid = fb * 256 + tid;                  // 0..2047
        int r = gid >> 4, c = gid & 15;
        float acc = 0.f;
#pragma unroll 8
        for (int k = 0; k < 128; k++) acc += W2[r * 128 + k] * Wc[k * 16 + c];
        W2c[gid] = acc;
        if (fb == 0) {
            if (tid < 16) {
                float a = bc[tid];
                for (int k = 0; k < 128; k++) a += b2[k] * Wc[k * 16 + tid];
                bc2[tid] = a;
            }
            if (tid < 64) {
                int c0 = tid * 2, c1 = c0 + 1;
                float sc0 = gamma[c0] * rsqrtf(rvar[c0] + BN_EPS);
                float sc1 = gamma[c1] * rsqrtf(rvar[c1] + BN_EPS);
                float sh0 = (b1[c0] - rmean[c0]) * sc0 + beta[c0];
                float sh1 = (b1[c1] - rmean[c1]) * sc1 + beta[c1];
                fusedq[tid] = make_float4(sc0, sh0, sc1, sh1);
            }
        }
    }
}

// ============ K2: block-local scan + dinv + cursor zero; LAST block scans partials ============
__global__ __launch_bounds__(256) void scan_kernel(const int* __restrict__ deg,
                                                   int* __restrict__ offs,
                                                   int* __restrict__ partials,
                                                   float* __restrict__ dinv,
                                                   int* __restrict__ cursor,
                                                   int* __restrict__ done) {
    __shared__ int s[256];
    __shared__ int isLast;
    int tid = threadIdx.x;
    int gid = blockIdx.x * 256 + tid;
    int v = (gid < N_NODES) ? deg[gid] : 0;
    if (gid < N_NODES) {
        dinv[gid] = rsqrtf((float)(v + 1));  // +1 self loop
        cursor[gid] = 0;
    }
    s[tid] = v;
    __syncthreads();
    for (int off = 1; off < 256; off <<= 1) {
        int t2 = (tid >= off) ? s[tid - off] : 0;
        __syncthreads();
        s[tid] += t2;
        __syncthreads();
    }
    if (gid <= N_NODES) offs[gid] = s[tid] - v;   // block-local exclusive
    if (tid == 255) partials[blockIdx.x] = s[255];

    __threadfence();                               // publish partials[bid] device-wide
    if (tid == 0) isLast = (atomicAdd(done, 1) == NBS - 1);
    __syncthreads();
    if (isLast) {
        __threadfence();                           // acquire all partials
        int pv = (tid < NBS) ? partials[tid] : 0;
        s[tid] = pv;
        __syncthreads();
        for (int off = 1; off < 256; off <<= 1) {
            int t2 = (tid >= off) ? s[tid - off] : 0;
            __syncthreads();
            s[tid] += t2;
            __syncthreads();
        }
        if (tid < NBS) partials[tid] = s[tid] - pv;  // exclusive totals
    }
}

// ============ K3: fill CSR (4 edges/thread) ============
__global__ __launch_bounds__(256) void fill_csr_kernel(const int* __restrict__ eidx,
                                                       const int* __restrict__ offs,
                                                       const int* __restrict__ part,
                                                       const float* __restrict__ dinv,
                                                       int* __restrict__ cursor,
                                                       int2* __restrict__ csr_sw) {
    const int4* src4 = (const int4*)eidx;
    const int4* dst4 = (const int4*)(eidx + N_EDGES);
    int t = blockIdx.x * 256 + threadIdx.x;
    int4 sv = src4[t];
    int4 dv = dst4[t];
    {
        int pos = offs[dv.x] + part[dv.x >> 8] + atomicAdd(&cursor[dv.x], 1);
        csr_sw[pos] = make_int2(sv.x, __float_as_int(dinv[sv.x]));
    }
    {
        int pos = offs[dv.y] + part[dv.y >> 8] + atomicAdd(&cursor[dv.y], 1);
        csr_sw[pos] = make_int2(sv.y, __float_as_int(dinv[sv.y]));
    }
    {
        int pos = offs[dv.z] + part[dv.z >> 8] + atomicAdd(&cursor[dv.z], 1);
        csr_sw[pos] = make_int2(sv.z, __float_as_int(dinv[sv.z]));
    }
    {
        int pos = offs[dv.w] + part[dv.w >> 8] + atomicAdd(&cursor[dv.w], 1);
        csr_sw[pos] = make_int2(sv.w, __float_as_int(dinv[sv.w]));
    }
}

// ============ K4: layer-1 agg (1 wave/node, 8-deep) + BN + ReLU + @W2c -> Z ============
__global__ __launch_bounds__(256) void agg1_kernel(const unsigned* __restrict__ Hb,
                                                   const int2* __restrict__ csr_sw,
                                                   const int* __restrict__ offs,
                                                   const int* __restrict__ part,
                                                   const float* __restrict__ dinv,
                                                   const float4* __restrict__ fusedq,
                                                   const float* __restrict__ W2c,
                                                   float* __restrict__ Z) {
    __shared__ float sH[4][128];
    int w = threadIdx.x >> 6, l = threadIdx.x & 63;
    int node = blockIdx.x * 4 + w;             // 12500*4 == 50000
    int beg = __builtin_amdgcn_readfirstlane(offs[node] + part[node >> 8]);
    int end = __builtin_amdgcn_readfirstlane(offs[node + 1] + part[(node + 1) >> 8]);
    float di = dinv[node];

    // W2c slice for the fused epilogue: lane (c=l&15, q=l>>4) owns k = q*32..+31 of column c
    int c = l & 15, q = l >> 4;
    float wreg[32];
#pragma unroll
    for (int i = 0; i < 32; i++) wreg[i] = W2c[(q * 32 + i) * 16 + c];

    unsigned hv = Hb[(size_t)node * 64 + l];
    float n2 = di * di;
    float acc0 = bf_lo(hv) * n2, acc1 = bf_hi(hv) * n2;  // self loop

    int e = beg;
    for (; e + 8 <= end; e += 8) {             // 8 full-wave row loads in flight
        int2 a0 = csr_sw[e];     int2 a1 = csr_sw[e + 1];
        int2 a2 = csr_sw[e + 2]; int2 a3 = csr_sw[e + 3];
        int2 a4 = csr_sw[e + 4]; int2 a5 = csr_sw[e + 5];
        int2 a6 = csr_sw[e + 6]; int2 a7 = csr_sw[e + 7];
        unsigned u0 = Hb[(size_t)a0.x * 64 + l];
        unsigned u1 = Hb[(size_t)a1.x * 64 + l];
        unsigned u2 = Hb[(size_t)a2.x * 64 + l];
        unsigned u3 = Hb[(size_t)a3.x * 64 + l];
        unsigned u4 = Hb[(size_t)a4.x * 64 + l];
        unsigned u5 = Hb[(size_t)a5.x * 64 + l];
        unsigned u6 = Hb[(size_t)a6.x * 64 + l];
        unsigned u7 = Hb[(size_t)a7.x * 64 + l];
        float w0 = __int_as_float(a0.y) * di, w1 = __int_as_float(a1.y) * di;
        float w2 = __int_as_float(a2.y) * di, w3 = __int_as_float(a3.y) * di;
        float w4 = __int_as_float(a4.y) * di, w5 = __int_as_float(a5.y) * di;
        float w6 = __int_as_float(a6.y) * di, w7 = __int_as_float(a7.y) * di;
        acc0 += bf_lo(u0) * w0 + bf_lo(u1) * w1 + bf_lo(u2) * w2 + bf_lo(u3) * w3
              + bf_lo(u4) * w4 + bf_lo(u5) * w5 + bf_lo(u6) * w6 + bf_lo(u7) * w7;
        acc1 += bf_hi(u0) * w0 + bf_hi(u1) * w1 + bf_hi(u2) * w2 + bf_hi(u3) * w3
              + bf_hi(u4) * w4 + bf_hi(u5) * w5 + bf_hi(u6) * w6 + bf_hi(u7) * w7;
    }
    while (e < end) {                          // masked 4-batch tail (parallel loads)
        int i1 = e + 1 < end ? e + 1 : end - 1;
        int i2 = e + 2 < end ? e + 2 : end - 1;
        int i3 = e + 3 < end ? e + 3 : end - 1;
        int2 a0 = csr_sw[e];  int2 a1 = csr_sw[i1];
        int2 a2 = csr_sw[i2]; int2 a3 = csr_sw[i3];
        unsigned u0 = Hb[(size_t)a0.x * 64 + l];
        unsigned u1 = Hb[(size_t)a1.x * 64 + l];
        unsigned u2 = Hb[(size_t)a2.x * 64 + l];
        unsigned u3 = Hb[(size_t)a3.x * 64 + l];
        float w0 = __int_as_float(a0.y) * di;
        float w1 = (e + 1 < end) ? __int_as_float(a1.y) * di : 0.f;
        float w2 = (e + 2 < end) ? __int_as_float(a2.y) * di : 0.f;
        float w3 = (e + 3 < end) ? __int_as_float(a3.y) * di : 0.f;
        acc0 += bf_lo(u0) * w0 + bf_lo(u1) * w1 + bf_lo(u2) * w2 + bf_lo(u3) * w3;
        acc1 += bf_hi(u0) * w0 + bf_hi(u1) * w1 + bf_hi(u2) * w2 + bf_hi(u3) * w3;
        e += 4;
    }

    // fused BN affine + ReLU (lane l holds features 2l, 2l+1)
    float4 qv = fusedq[l];
    float a0 = fmaxf(acc0 * qv.x + qv.y, 0.f);
    float a1 = fmaxf(acc1 * qv.z + qv.w, 0.f);

    // in-wave transpose through LDS (wave-private region, no barrier)
    ((float2*)sH[w])[l] = make_float2(a0, a1);
    float z = 0.f;
    const float4* row4 = (const float4*)&sH[w][q * 32];
#pragma unroll
    for (int i = 0; i < 8; i++) {
        float4 v = row4[i];
        z += v.x * wreg[i * 4] + v.y * wreg[i * 4 + 1]
           + v.z * wreg[i * 4 + 2] + v.w * wreg[i * 4 + 3];
    }
    z += __shfl_xor(z, 16);
    z += __shfl_xor(z, 32);
    if (l < 16) Z[(size_t)node * NCLS + l] = z;
}

// ============ K5: layer-2 agg on Z (16-wide) + bc2 -> out ============
__global__ __launch_bounds__(256) void agg2_kernel(const float* __restrict__ Z,
                                                   const int2* __restrict__ csr_sw,
                                                   const int* __restrict__ offs,
                                                   const int* __restrict__ part,
                                                   const float* __restrict__ dinv,
                                                   const float* __restrict__ bc2,
                                                   float* __restrict__ out) {
    int grp = threadIdx.x >> 4, c = threadIdx.x & 15;
    int node = blockIdx.x * 16 + grp;          // 3125*16 == 50000
    int beg = offs[node] + part[node >> 8];
    int end = offs[node + 1] + part[(node + 1) >> 8];
    float di = dinv[node];

    float acc = Z[(size_t)node * NCLS + c] * di * di;
    int e = beg;
    for (; e + 8 <= end; e += 8) {
        int2 a0 = csr_sw[e],     a1 = csr_sw[e + 1];
        int2 a2 = csr_sw[e + 2], a3 = csr_sw[e + 3];
        int2 a4 = csr_sw[e + 4], a5 = csr_sw[e + 5];
        int2 a6 = csr_sw[e + 6], a7 = csr_sw[e + 7];
        float v0 = Z[(size_t)a0.x * NCLS + c];
        float v1 = Z[(size_t)a1.x * NCLS + c];
        float v2 = Z[(size_t)a2.x * NCLS + c];
        float v3 = Z[(size_t)a3.x * NCLS + c];
        float v4 = Z[(size_t)a4.x * NCLS + c];
        float v5 = Z[(size_t)a5.x * NCLS + c];
        float v6 = Z[(size_t)a6.x * NCLS + c];
        float v7 = Z[(size_t)a7.x * NCLS + c];
        acc += v0 * (__int_as_float(a0.y) * di) + v1 * (__int_as_float(a1.y) * di)
             + v2 * (__int_as_float(a2.y) * di) + v3 * (__int_as_float(a3.y) * di)
             + v4 * (__int_as_float(a4.y) * di) + v5 * (__int_as_float(a5.y) * di)
             + v6 * (__int_as_float(a6.y) * di) + v7 * (__int_as_float(a7.y) * di);
    }
    for (; e < end; e++) {
        int2 a = csr_sw[e];
        acc += Z[(size_t)a.x * NCLS + c] * (__int_as_float(a.y) * di);
    }
    out[(size_t)node * NCLS + c] = acc + bc2[c];
}

// ---------------- Launch ----------------
extern "C" void kernel_launch(void* const* d_in, const int* in_sizes, int n_in,
                              void* d_out, int out_size, void* d_ws, size_t ws_size,
                              hipStream_t stream) {
    const float* seq   = (const float*)d_in[0];
    const int*   eidx  = (const int*)d_in[1];
    const float* W1    = (const float*)d_in[2];
    const float* b1    = (const float*)d_in[3];
    const float* gamma = (const float*)d_in[4];
    const float* beta  = (const float*)d_in[5];
    const float* rmean = (const float*)d_in[6];
    const float* rvar  = (const float*)d_in[7];
    const float* W2    = (const float*)d_in[8];
    const float* b2    = (const float*)d_in[9];
    const float* Wc    = (const float*)d_in[10];
    const float* bc    = (const float*)d_in[11];

    char* ws = (char*)d_ws;
    size_t off = 0;
    auto alloc = [&](size_t bytes) -> void* {
        void* p = ws + off;
        off = (off + bytes + 255) & ~(size_t)255;
        return p;
    };
    int*    ctl      = (int*)alloc(256);                    // [0]=done counter
    int*    deg      = (int*)alloc(N_NODES * 4);            // contiguous with ctl: one memset
    int*    cursor   = (int*)alloc(N_NODES * 4);
    int*    offs     = (int*)alloc((N_NODES + 1) * 4);
    int*    partials = (int*)alloc(256 * 4);
    float*  dinv     = (float*)alloc(N_NODES * 4);
    int2*   csr_sw   = (int2*)alloc((size_t)N_EDGES * 8);
    float*  W2c      = (float*)alloc(FDIM * NCLS * 4);
    float*  bc2      = (float*)alloc(NCLS * 4);
    float4* fusedq   = (float4*)alloc(64 * 16);
    unsigned* bufA   = (unsigned*)alloc((size_t)N_NODES * (FDIM / 2) * 4);  // bf16 packed
    float*  Zbuf     = (float*)alloc((size_t)N_NODES * NCLS * 4);

    hipMemsetAsync(ctl, 0, 256 + (size_t)N_NODES * 4, stream);   // ctl + deg
    gemm_count_fold_kernel<<<NBG + 625 + 8, 256, 0, stream>>>(
        seq, W1, bufA, eidx, deg, W2, Wc, b1, b2, bc, gamma, beta, rmean, rvar,
        W2c, bc2, fusedq);
    scan_kernel<<<NBS, 256, 0, stream>>>(deg, offs, partials, dinv, cursor, ctl);
    fill_csr_kernel<<<625, 256, 0, stream>>>(eidx, offs, partials, dinv, cursor, csr_sw);
    agg1_kernel<<<N_NODES / 4, 256, 0, stream>>>(bufA, csr_sw, offs, partials,
                                                 dinv, fusedq, W2c, Zbuf);
    agg2_kernel<<<N_NODES / 16, 256, 0, stream>>>(Zbuf, csr_sw, offs, partials,
                                                  dinv, bc2, (float*)d_out);
}

// Round 9
// 229.224 us; speedup vs baseline: 2.9724x; 1.0068x over previous
//
#include <hip/hip_runtime.h>
#include <math.h>

#define N_NODES 50000
#define N_EDGES 640000
#define FDIM 128
#define NCLS 16
#define BN_EPS 1e-5f
#define NBS 196           // ceil(50000/256) scan blocks
#define NBG 782           // ceil(50000/64) gemm tiles

typedef __attribute__((ext_vector_type(8))) short bf16x8;
typedef __attribute__((ext_vector_type(4))) float f32x4;

// ---- bf16 pack/unpack (RNE) ----
__device__ __forceinline__ unsigned pack_bf16x2(float lo, float hi) {
    unsigned ul = __float_as_uint(lo);
    unsigned uh = __float_as_uint(hi);
    ul += 0x7fff + ((ul >> 16) & 1);
    uh += 0x7fff + ((uh >> 16) & 1);
    return (ul >> 16) | (uh & 0xffff0000u);
}
__device__ __forceinline__ unsigned short bf16_rne(float x) {
    unsigned u = __float_as_uint(x);
    u += 0x7fff + ((u >> 16) & 1);
    return (unsigned short)(u >> 16);
}
__device__ __forceinline__ float bf_lo(unsigned u) { return __uint_as_float(u << 16); }
__device__ __forceinline__ float bf_hi(unsigned u) { return __uint_as_float(u & 0xffff0000u); }

// ============ K1: MFMA gemm (blocks 0..781) | count_deg (782..1406) | fold (1407..1414) ============
// gemm: 64 rows/block, 4 waves x 16 rows. W1 packed hi/lo bf16 fragments in LDS (64KB).
// hi/lo split of BOTH operands (3 mfma/tile, drop lo*lo <= 2^-18) keeps f32-level accuracy.
__global__ __launch_bounds__(256) void gemm_count_fold_kernel(
        const float* __restrict__ seq, const float* __restrict__ W1,
        unsigned* __restrict__ bufA,
        const int* __restrict__ eidx, int* __restrict__ deg,
        const float* __restrict__ W2, const float* __restrict__ Wc,
        const float* __restrict__ b1, const float* __restrict__ b2,
        const float* __restrict__ bc, const float* __restrict__ gamma,
        const float* __restrict__ beta, const float* __restrict__ rmean,
        const float* __restrict__ rvar,
        float* __restrict__ W2c, float* __restrict__ bc2, float4* __restrict__ fusedq) {
    __shared__ __align__(16) char smem[65536];
    int tid = threadIdx.x;
    int bid = blockIdx.x;

    if (bid < NBG) {
        // -------- stage 1: pack W1 into LDS as hi/lo bf16 fragments --------
        // frag index fi = ct*256 + kt*64 + lane; entry j: W1[kt*32+(lane>>4)*8+j][ct*16+(lane&15)]
        bf16x8* WH = (bf16x8*)smem;              // 2048 frags * 16B = 32KB
        bf16x8* WL = (bf16x8*)(smem + 32768);    // 32KB
        {
            int f0 = tid * 8;
#pragma unroll
            for (int fo = 0; fo < 8; fo++) {
                int fi = f0 + fo;
                int lane = fi & 63, kt = (fi >> 6) & 3, ct = fi >> 8;
                int kbase = kt * 32 + (lane >> 4) * 8;
                int col = ct * 16 + (lane & 15);
                short h[8], lo[8];
#pragma unroll
                for (int j = 0; j < 8; j++) {
                    float wv = W1[(kbase + j) * 128 + col];
                    unsigned short hs = bf16_rne(wv);
                    float rem = wv - __uint_as_float(((unsigned)hs) << 16);
                    h[j] = (short)hs;
                    lo[j] = (short)bf16_rne(rem);
                }
                WH[fi] = *(bf16x8*)h;
                WL[fi] = *(bf16x8*)lo;
            }
        }
        __syncthreads();

        // -------- stage 2: MFMA main loop --------
        int w = tid >> 6, l = tid & 63;
        int la = l & 15, q = l >> 4;
        int r0 = bid * 64;
        int arow = r0 + w * 16 + la;             // A-operand row for this lane
        bool rowok = arow < N_NODES;
        const float4* X4 = (const float4*)seq;

        float4 xr[8];
#pragma unroll
        for (int kt = 0; kt < 4; kt++) {
            float4 z4 = make_float4(0.f, 0.f, 0.f, 0.f);
            xr[kt * 2]     = rowok ? X4[arow * 32 + kt * 8 + q * 2]     : z4;
            xr[kt * 2 + 1] = rowok ? X4[arow * 32 + kt * 8 + q * 2 + 1] : z4;
        }
        bf16x8 ah[4], al[4];
#pragma unroll
        for (int kt = 0; kt < 4; kt++) {
            const float* xv = (const float*)&xr[kt * 2];
#pragma unroll
            for (int j = 0; j < 8; j++) {
                float v = xv[j];
                unsigned short hs = bf16_rne(v);
                float rem = v - __uint_as_float(((unsigned)hs) << 16);
                ah[kt][j] = (short)hs;
                al[kt][j] = (short)bf16_rne(rem);
            }
        }
        f32x4 acc[8];
#pragma unroll
        for (int ct = 0; ct < 8; ct++) acc[ct] = (f32x4){0.f, 0.f, 0.f, 0.f};

#pragma unroll
        for (int kt = 0; kt < 4; kt++) {
#pragma unroll
            for (int ct = 0; ct < 8; ct++) {
                bf16x8 bh = WH[(ct * 4 + kt) * 64 + l];
                bf16x8 bl = WL[(ct * 4 + kt) * 64 + l];
                acc[ct] = __builtin_amdgcn_mfma_f32_16x16x32_bf16(ah[kt], bh, acc[ct], 0, 0, 0);
                acc[ct] = __builtin_amdgcn_mfma_f32_16x16x32_bf16(ah[kt], bl, acc[ct], 0, 0, 0);
                acc[ct] = __builtin_amdgcn_mfma_f32_16x16x32_bf16(al[kt], bh, acc[ct], 0, 0, 0);
            }
        }
        __syncthreads();                          // all waves done reading W frags

        // -------- stage 3: repack C through LDS -> bf16 bufA --------
        float* sC = (float*)smem;                 // 64 rows x stride 132 = 33.8KB
#pragma unroll
        for (int ct = 0; ct < 8; ct++)
#pragma unroll
            for (int r = 0; r < 4; r++)
                sC[(w * 16 + q * 4 + r) * 132 + ct * 16 + la] = acc[ct][r];
        __syncthreads();

        int trow = tid >> 2, tcb = (tid & 3) * 32;
        int grow = r0 + trow;
        if (grow < N_NODES) {
            const float* sr = sC + trow * 132 + tcb;
            unsigned ob[16];
#pragma unroll
            for (int t = 0; t < 16; t++) ob[t] = pack_bf16x2(sr[2 * t], sr[2 * t + 1]);
            uint4* dp = (uint4*)(bufA + (size_t)grow * 64 + (tid & 3) * 16);
#pragma unroll
            for (int g = 0; g < 4; g++)
                dp[g] = make_uint4(ob[g * 4], ob[g * 4 + 1], ob[g * 4 + 2], ob[g * 4 + 3]);
        }
    } else if (bid < NBG + 625) {
        // -------- count in-degrees: 4 edges/thread, int4 reads --------
        const int4* dst4 = (const int4*)(eidx + N_EDGES);
        int t = (bid - NBG) * 256 + tid;
        int4 d = dst4[t];
        atomicAdd(&deg[d.x], 1);
        atomicAdd(&deg[d.y], 1);
        atomicAdd(&deg[d.z], 1);
        atomicAdd(&deg[d.w], 1);
    } else {
        // -------- fold: W2c = W2@Wc, bc2 = b2@Wc + bc, BN affine --------
        int fb = bid - (NBG + 625);                // 0..7
        int gid = fb * 256 + tid;                  // 0..2047
        int r = gid >> 4, c = gid & 15;
        float acc = 0.f;
#pragma unroll 8
        for (int k = 0; k < 128; k++) acc += W2[r * 128 + k] * Wc[k * 16 + c];
        W2c[gid] = acc;
        if (fb == 0) {
            if (tid < 16) {
                float a = bc[tid];
                for (int k = 0; k < 128; k++) a += b2[k] * Wc[k * 16 + tid];
                bc2[tid] = a;
            }
            if (tid < 64) {
                int c0 = tid * 2, c1 = c0 + 1;
                float sc0 = gamma[c0] * rsqrtf(rvar[c0] + BN_EPS);
                float sc1 = gamma[c1] * rsqrtf(rvar[c1] + BN_EPS);
                float sh0 = (b1[c0] - rmean[c0]) * sc0 + beta[c0];
                float sh1 = (b1[c1] - rmean[c1]) * sc1 + beta[c1];
                fusedq[tid] = make_float4(sc0, sh0, sc1, sh1);
            }
        }
    }
}

// ============ K2: block-local scan + dinv + cursor zero; LAST block scans partials ============
__global__ __launch_bounds__(256) void scan_kernel(const int* __restrict__ deg,
                                                   int* __restrict__ offs,
                                                   int* __restrict__ partials,
                                                   float* __restrict__ dinv,
                                                   int* __restrict__ cursor,
                                                   int* __restrict__ done) {
    __shared__ int s[256];
    __shared__ int isLast;
    int tid = threadIdx.x;
    int gid = blockIdx.x * 256 + tid;
    int v = (gid < N_NODES) ? deg[gid] : 0;
    if (gid < N_NODES) {
        dinv[gid] = rsqrtf((float)(v + 1));  // +1 self loop
        cursor[gid] = 0;
    }
    s[tid] = v;
    __syncthreads();
    for (int off = 1; off < 256; off <<= 1) {
        int t2 = (tid >= off) ? s[tid - off] : 0;
        __syncthreads();
        s[tid] += t2;
        __syncthreads();
    }
    if (gid <= N_NODES) offs[gid] = s[tid] - v;   // block-local exclusive
    if (tid == 255) partials[blockIdx.x] = s[255];

    __threadfence();                               // publish partials[bid] device-wide
    if (tid == 0) isLast = (atomicAdd(done, 1) == NBS - 1);
    __syncthreads();
    if (isLast) {
        __threadfence();                           // acquire all partials
        int pv = (tid < NBS) ? partials[tid] : 0;
        s[tid] = pv;
        __syncthreads();
        for (int off = 1; off < 256; off <<= 1) {
            int t2 = (tid >= off) ? s[tid - off] : 0;
            __syncthreads();
            s[tid] += t2;
            __syncthreads();
        }
        if (tid < NBS) partials[tid] = s[tid] - pv;  // exclusive totals
    }
}

// ============ K3: fill CSR (4 edges/thread) ============
__global__ __launch_bounds__(256) void fill_csr_kernel(const int* __restrict__ eidx,
                                                       const int* __restrict__ offs,
                                                       const int* __restrict__ part,
                                                       const float* __restrict__ dinv,
                                                       int* __restrict__ cursor,
                                                       int2* __restrict__ csr_sw) {
    const int4* src4 = (const int4*)eidx;
    const int4* dst4 = (const int4*)(eidx + N_EDGES);
    int t = blockIdx.x * 256 + threadIdx.x;
    int4 sv = src4[t];
    int4 dv = dst4[t];
    {
        int pos = offs[dv.x] + part[dv.x >> 8] + atomicAdd(&cursor[dv.x], 1);
        csr_sw[pos] = make_int2(sv.x, __float_as_int(dinv[sv.x]));
    }
    {
        int pos = offs[dv.y] + part[dv.y >> 8] + atomicAdd(&cursor[dv.y], 1);
        csr_sw[pos] = make_int2(sv.y, __float_as_int(dinv[sv.y]));
    }
    {
        int pos = offs[dv.z] + part[dv.z >> 8] + atomicAdd(&cursor[dv.z], 1);
        csr_sw[pos] = make_int2(sv.z, __float_as_int(dinv[sv.z]));
    }
    {
        int pos = offs[dv.w] + part[dv.w >> 8] + atomicAdd(&cursor[dv.w], 1);
        csr_sw[pos] = make_int2(sv.w, __float_as_int(dinv[sv.w]));
    }
}

// ============ K4: layer-1 agg (1 wave/node, 8-deep) + BN + ReLU + @W2c -> Z ============
__global__ __launch_bounds__(256) void agg1_kernel(const unsigned* __restrict__ Hb,
                                                   const int2* __restrict__ csr_sw,
                                                   const int* __restrict__ offs,
                                                   const int* __restrict__ part,
                                                   const float* __restrict__ dinv,
                                                   const float4* __restrict__ fusedq,
                                                   const float* __restrict__ W2c,
                                                   float* __restrict__ Z) {
    __shared__ float sH[4][128];
    int w = threadIdx.x >> 6, l = threadIdx.x & 63;
    int node = blockIdx.x * 4 + w;             // 12500*4 == 50000
    int beg = __builtin_amdgcn_readfirstlane(offs[node] + part[node >> 8]);
    int end = __builtin_amdgcn_readfirstlane(offs[node + 1] + part[(node + 1) >> 8]);
    float di = dinv[node];

    // W2c slice for the fused epilogue: lane (c=l&15, q=l>>4) owns k = q*32..+31 of column c
    int c = l & 15, q = l >> 4;
    float wreg[32];
#pragma unroll
    for (int i = 0; i < 32; i++) wreg[i] = W2c[(q * 32 + i) * 16 + c];

    unsigned hv = Hb[(size_t)node * 64 + l];
    float n2 = di * di;
    float acc0 = bf_lo(hv) * n2, acc1 = bf_hi(hv) * n2;  // self loop

    int e = beg;
    for (; e + 8 <= end; e += 8) {             // 8 full-wave row loads in flight
        int2 a0 = csr_sw[e];     int2 a1 = csr_sw[e + 1];
        int2 a2 = csr_sw[e + 2]; int2 a3 = csr_sw[e + 3];
        int2 a4 = csr_sw[e + 4]; int2 a5 = csr_sw[e + 5];
        int2 a6 = csr_sw[e + 6]; int2 a7 = csr_sw[e + 7];
        unsigned u0 = Hb[(size_t)a0.x * 64 + l];
        unsigned u1 = Hb[(size_t)a1.x * 64 + l];
        unsigned u2 = Hb[(size_t)a2.x * 64 + l];
        unsigned u3 = Hb[(size_t)a3.x * 64 + l];
        unsigned u4 = Hb[(size_t)a4.x * 64 + l];
        unsigned u5 = Hb[(size_t)a5.x * 64 + l];
        unsigned u6 = Hb[(size_t)a6.x * 64 + l];
        unsigned u7 = Hb[(size_t)a7.x * 64 + l];
        float w0 = __int_as_float(a0.y) * di, w1 = __int_as_float(a1.y) * di;
        float w2 = __int_as_float(a2.y) * di, w3 = __int_as_float(a3.y) * di;
        float w4 = __int_as_float(a4.y) * di, w5 = __int_as_float(a5.y) * di;
        float w6 = __int_as_float(a6.y) * di, w7 = __int_as_float(a7.y) * di;
        acc0 += bf_lo(u0) * w0 + bf_lo(u1) * w1 + bf_lo(u2) * w2 + bf_lo(u3) * w3
              + bf_lo(u4) * w4 + bf_lo(u5) * w5 + bf_lo(u6) * w6 + bf_lo(u7) * w7;
        acc1 += bf_hi(u0) * w0 + bf_hi(u1) * w1 + bf_hi(u2) * w2 + bf_hi(u3) * w3
              + bf_hi(u4) * w4 + bf_hi(u5) * w5 + bf_hi(u6) * w6 + bf_hi(u7) * w7;
    }
    while (e < end) {                          // masked 4-batch tail (parallel loads)
        int i1 = e + 1 < end ? e + 1 : end - 1;
        int i2 = e + 2 < end ? e + 2 : end - 1;
        int i3 = e + 3 < end ? e + 3 : end - 1;
        int2 a0 = csr_sw[e];  int2 a1 = csr_sw[i1];
        int2 a2 = csr_sw[i2]; int2 a3 = csr_sw[i3];
        unsigned u0 = Hb[(size_t)a0.x * 64 + l];
        unsigned u1 = Hb[(size_t)a1.x * 64 + l];
        unsigned u2 = Hb[(size_t)a2.x * 64 + l];
        unsigned u3 = Hb[(size_t)a3.x * 64 + l];
        float w0 = __int_as_float(a0.y) * di;
        float w1 = (e + 1 < end) ? __int_as_float(a1.y) * di : 0.f;
        float w2 = (e + 2 < end) ? __int_as_float(a2.y) * di : 0.f;
        float w3 = (e + 3 < end) ? __int_as_float(a3.y) * di : 0.f;
        acc0 += bf_lo(u0) * w0 + bf_lo(u1) * w1 + bf_lo(u2) * w2 + bf_lo(u3) * w3;
        acc1 += bf_hi(u0) * w0 + bf_hi(u1) * w1 + bf_hi(u2) * w2 + bf_hi(u3) * w3;
        e += 4;
    }

    // fused BN affine + ReLU (lane l holds features 2l, 2l+1)
    float4 qv = fusedq[l];
    float a0 = fmaxf(acc0 * qv.x + qv.y, 0.f);
    float a1 = fmaxf(acc1 * qv.z + qv.w, 0.f);

    // in-wave transpose through LDS (wave-private region, no barrier)
    ((float2*)sH[w])[l] = make_float2(a0, a1);
    float z = 0.f;
    const float4* row4 = (const float4*)&sH[w][q * 32];
#pragma unroll
    for (int i = 0; i < 8; i++) {
        float4 v = row4[i];
        z += v.x * wreg[i * 4] + v.y * wreg[i * 4 + 1]
           + v.z * wreg[i * 4 + 2] + v.w * wreg[i * 4 + 3];
    }
    z += __shfl_xor(z, 16);
    z += __shfl_xor(z, 32);
    if (l < 16) Z[(size_t)node * NCLS + l] = z;
}

// ============ K5: layer-2 agg on Z (16-wide) + bc2 -> out ============
__global__ __launch_bounds__(256) void agg2_kernel(const float* __restrict__ Z,
                                                   const int2* __restrict__ csr_sw,
                                                   const int* __restrict__ offs,
                                                   const int* __restrict__ part,
                                                   const float* __restrict__ dinv,
                                                   const float* __restrict__ bc2,
                                                   float* __restrict__ out) {
    int grp = threadIdx.x >> 4, c = threadIdx.x & 15;
    int node = blockIdx.x * 16 + grp;          // 3125*16 == 50000
    int beg = offs[node] + part[node >> 8];
    int end = offs[node + 1] + part[(node + 1) >> 8];
    float di = dinv[node];

    float acc = Z[(size_t)node * NCLS + c] * di * di;
    int e = beg;
    for (; e + 8 <= end; e += 8) {
        int2 a0 = csr_sw[e],     a1 = csr_sw[e + 1];
        int2 a2 = csr_sw[e + 2], a3 = csr_sw[e + 3];
        int2 a4 = csr_sw[e + 4], a5 = csr_sw[e + 5];
        int2 a6 = csr_sw[e + 6], a7 = csr_sw[e + 7];
        float v0 = Z[(size_t)a0.x * NCLS + c];
        float v1 = Z[(size_t)a1.x * NCLS + c];
        float v2 = Z[(size_t)a2.x * NCLS + c];
        float v3 = Z[(size_t)a3.x * NCLS + c];
        float v4 = Z[(size_t)a4.x * NCLS + c];
        float v5 = Z[(size_t)a5.x * NCLS + c];
        float v6 = Z[(size_t)a6.x * NCLS + c];
        float v7 = Z[(size_t)a7.x * NCLS + c];
        acc += v0 * (__int_as_float(a0.y) * di) + v1 * (__int_as_float(a1.y) * di)
             + v2 * (__int_as_float(a2.y) * di) + v3 * (__int_as_float(a3.y) * di)
             + v4 * (__int_as_float(a4.y) * di) + v5 * (__int_as_float(a5.y) * di)
             + v6 * (__int_as_float(a6.y) * di) + v7 * (__int_as_float(a7.y) * di);
    }
    for (; e < end; e++) {
        int2 a = csr_sw[e];
        acc += Z[(size_t)a.x * NCLS + c] * (__int_as_float(a.y) * di);
    }
    out[(size_t)node * NCLS + c] = acc + bc2[c];
}

// ---------------- Launch ----------------
extern "C" void kernel_launch(void* const* d_in, const int* in_sizes, int n_in,
                              void* d_out, int out_size, void* d_ws, size_t ws_size,
                              hipStream_t stream) {
    const float* seq   = (const float*)d_in[0];
    const int*   eidx  = (const int*)d_in[1];
    const float* W1    = (const float*)d_in[2];
    const float* b1    = (const float*)d_in[3];
    const float* gamma = (const float*)d_in[4];
    const float* beta  = (const float*)d_in[5];
    const float* rmean = (const float*)d_in[6];
    const float* rvar  = (const float*)d_in[7];
    const float* W2    = (const float*)d_in[8];
    const float* b2    = (const float*)d_in[9];
    const float* Wc    = (const float*)d_in[10];
    const float* bc    = (const float*)d_in[11];

    char* ws = (char*)d_ws;
    size_t off = 0;
    auto alloc = [&](size_t bytes) -> void* {
        void* p = ws + off;
        off = (off + bytes + 255) & ~(size_t)255;
        return p;
    };
    int*    ctl      = (int*)alloc(256);                    // [0]=done counter
    int*    deg      = (int*)alloc(N_NODES * 4);            // contiguous with ctl: one memset
    int*    cursor   = (int*)alloc(N_NODES * 4);
    int*    offs     = (int*)alloc((N_NODES + 1) * 4);
    int*    partials = (int*)alloc(256 * 4);
    float*  dinv     = (float*)alloc(N_NODES * 4);
    int2*   csr_sw   = (int2*)alloc((size_t)N_EDGES * 8);
    float*  W2c      = (float*)alloc(FDIM * NCLS * 4);
    float*  bc2      = (float*)alloc(NCLS * 4);
    float4* fusedq   = (float4*)alloc(64 * 16);
    unsigned* bufA   = (unsigned*)alloc((size_t)N_NODES * (FDIM / 2) * 4);  // bf16 packed
    float*  Zbuf     = (float*)alloc((size_t)N_NODES * NCLS * 4);

    hipMemsetAsync(ctl, 0, 256 + (size_t)N_NODES * 4, stream);   // ctl + deg
    gemm_count_fold_kernel<<<NBG + 625 + 8, 256, 0, stream>>>(
        seq, W1, bufA, eidx, deg, W2, Wc, b1, b2, bc, gamma, beta, rmean, rvar,
        W2c, bc2, fusedq);
    scan_kernel<<<NBS, 256, 0, stream>>>(deg, offs, partials, dinv, cursor, ctl);
    fill_csr_kernel<<<625, 256, 0, stream>>>(eidx, offs, partials, dinv, cursor, csr_sw);
    agg1_kernel<<<N_NODES / 4, 256, 0, stream>>>(bufA, csr_sw, offs, partials,
                                                 dinv, fusedq, W2c, Zbuf);
    agg2_kernel<<<N_NODES / 16, 256, 0, stream>>>(Zbuf, csr_sw, offs, partials,
                                                  dinv, bc2, (float*)d_out);
}